// Round 5
// baseline (11299.938 us; speedup 1.0000x reference)
//
#include <hip/hip_runtime.h>
#include <hip/hip_bf16.h>
#include <cstdint>

// Problem constants
#define BB   64
#define TT   128
#define KK   4
#define LL   128
#define SS   64
#define AA   64
#define DQN  32
#define UU   256
#define NAOUT 164
#define WDIM 300
#define PDIM 64
#define ADIM 64

typedef unsigned short ushort_t;
typedef unsigned int   uint_t;

__device__ __forceinline__ float bf2f(ushort_t s) {
    return __uint_as_float(((uint_t)s) << 16);
}
__device__ __forceinline__ ushort_t f2bf(float x) {
    __hip_bfloat16 h = __float2bfloat16(x);
    return *reinterpret_cast<ushort_t*>(&h);
}
__device__ __forceinline__ float sigm(float x) { return 1.0f / (1.0f + expf(-x)); }

// Dual-dtype load: F32=true -> buffer holds float32; false -> bf16.
template<bool F32>
__device__ __forceinline__ float ld1(const void* p_, size_t i) {
    if constexpr (F32) return reinterpret_cast<const float*>(p_)[i];
    else               return bf2f(reinterpret_cast<const ushort_t*>(p_)[i]);
}

struct P {
    // int inputs
    const int *tree_word_id, *tree_pos_id, *token_word_id, *token_pos_id, *history_action_id,
              *buff_top_id, *deque_word_id, *deque_pos_id, *deque_length, *children_order,
              *stack_order, *stack_length, *token_length, *history_action_length;
    // float-family params (dtype resolved at runtime)
    const void *word_emb, *pos_emb, *act_emb, *wd_W, *wd_b, *tree_W, *tree_b,
        *stack0_W, *stack0_b, *stack1_W, *stack1_b, *fw0_W, *fw0_b, *bw0_W, *bw0_b,
        *fw1_W, *fw1_b, *bw1_W, *bw1_b, *act0_W, *act0_b, *act1_W, *act1_b,
        *dq0_W, *dq0_b, *dq1_W, *dq1_b, *fin_W, *fin_b;
    // workspace
    int* flag;                          // [0]: 0 = bf16 world, 1 = f32 world
    float *stack_h, *fw1_h, *fw_top, *bw_top, *bw_bottom, *act_h, *dq_h;  // f32
    float *tree_e;                      // f32! (tree dynamics are chaotic — no bf16 seed)
    ushort_t *token_e, *deque_e, *x1;   // bf16 (contractive chains tolerate rounding)
    float *H, *C;                       // f32
};

// ---------------------------------------------------------------------------
// dtype detector (validated: bf16 world detected in rounds 3/4)
// ---------------------------------------------------------------------------
__global__ void detect_kernel(const uint_t* w, int* flag) {
    __shared__ int cnt;
    if (threadIdx.x == 0) cnt = 0;
    __syncthreads();
    int local = 0;
    for (int i = threadIdx.x; i < 256; i += 64) {
        uint_t lo = w[i] & 0xFFFFu;
        uint_t e  = (lo >> 7) & 0xFFu;
        if (lo == 0u || (e >= 0x6Cu && e <= 0x7Fu)) local++;
    }
    atomicAdd(&cnt, local);
    __syncthreads();
    if (threadIdx.x == 0) flag[0] = (cnt >= 200) ? 0 : 1;
}

__global__ void sentinel_kernel(void* out, float v) {
    if (threadIdx.x == 0) {
        reinterpret_cast<float*>(out)[0] = v;
        reinterpret_cast<__hip_bfloat16*>(out)[2] = __float2bfloat16(v);
    }
}

// ---------------------------------------------------------------------------
// Embedding (one row per block): e = relu(concat(word_emb[wid], pos_emb[pid]) @ wd_W + wd_b)
// Tree rows -> f32 output; token/deque rows -> bf16 output.
// ---------------------------------------------------------------------------
template<bool F32>
__device__ void embed_impl(const P& p, float* s_e) {
    const int u   = threadIdx.x;
    const int row = blockIdx.x;

    const int* wid; const int* pid; int rowbase; int which;
    float* out_f = nullptr; ushort_t* out_b = nullptr;
    if (row < BB * TT) {
        wid = p.tree_word_id; pid = p.tree_pos_id; rowbase = row; which = 0;
        out_f = p.tree_e;
    } else if (row < BB * TT + BB * LL) {
        wid = p.token_word_id; pid = p.token_pos_id; rowbase = row - BB * TT; which = 1;
        out_b = p.token_e;
    } else {
        wid = p.deque_word_id; pid = p.deque_pos_id; rowbase = row - BB * TT - BB * LL; which = 2;
        out_b = p.deque_e;
    }

    const int w  = wid[rowbase];
    const int pp = pid[rowbase];
    for (int e = u; e < WDIM + PDIM; e += 256) {
        s_e[e] = (e < WDIM) ? ld1<F32>(p.word_emb, (size_t)w * WDIM + e)
                            : ld1<F32>(p.pos_emb, (size_t)pp * PDIM + (e - WDIM));
    }
    __syncthreads();

    float acc = ld1<F32>(p.wd_b, u);
    for (int r = 0; r < WDIM + PDIM; ++r)
        acc = fmaf(s_e[r], ld1<F32>(p.wd_W, (size_t)r * UU + u), acc);
    acc = fmaxf(acc, 0.f);
    if (which == 0) out_f[(size_t)rowbase * UU + u] = acc;
    else            out_b[(size_t)rowbase * UU + u] = f2bf(acc);
}

__global__ __launch_bounds__(256) void embed_kernel(P p) {
    __shared__ __align__(16) float s_e[384];
    if (p.flag[0] == 1) embed_impl<true>(p, s_e);
    else                embed_impl<false>(p, s_e);
}

// ---------------------------------------------------------------------------
// One LSTM step, fused gates+combine. Thread u owns unit u (gate cols
// u, 256+u, 512+u, 768+u). s_xh = [x (INT-256) | h (256)].
// ---------------------------------------------------------------------------
template<int INT, bool F32>
__device__ __forceinline__ float lstm_step(const void* __restrict__ W,
                                           const void* __restrict__ bias,
                                           const float* __restrict__ s_xh,
                                           float& c) {
    const int u = threadIdx.x;
    float zi = 0.f, zj = 0.f, zf = 0.f, zo = 0.f;
    for (int r = 0; r < INT; ++r) {
        const float xv = s_xh[r];
        const size_t ro = (size_t)r * 1024;
        zi = fmaf(xv, ld1<F32>(W, ro + u),       zi);
        zj = fmaf(xv, ld1<F32>(W, ro + 256 + u), zj);
        zf = fmaf(xv, ld1<F32>(W, ro + 512 + u), zf);
        zo = fmaf(xv, ld1<F32>(W, ro + 768 + u), zo);
    }
    zi += ld1<F32>(bias, u);
    zj += ld1<F32>(bias, 256 + u);
    zf += ld1<F32>(bias, 512 + u);
    zo += ld1<F32>(bias, 768 + u);
    const float nc = c * sigm(zf + 1.0f) + sigm(zi) * tanhf(zj);
    c = nc;
    return tanhf(nc) * sigm(zo);
}

// ---------------------------------------------------------------------------
// Phase 1
// ---------------------------------------------------------------------------
template<bool F32>
__device__ void run_tree(int b, const P& p, float* smem) {
    const int u = threadIdx.x;
    float* s_x  = smem;          // 256
    float* s_hj = smem + 256;    // 256
    float* s_hk = smem + 512;    // 1024
    float* H = p.H;
    float* C = p.C;
    H[(size_t)b * UU + u] = 0.f;
    C[(size_t)b * UU + u] = 0.f;

    const void* W    = p.tree_W;  // (512,1024): cols [0,768)=i|j|o, [768,1024)=f
    const void* bias = p.tree_b;

    for (int i = 0; i < TT; ++i) {
        const int* co = p.children_order + ((size_t)b * TT + i) * KK;
        const int i0 = co[0], i1 = co[1], i2 = co[2], i3 = co[3];
        const float h0 = H[((size_t)i0 * BB + b) * UU + u];
        const float h1 = H[((size_t)i1 * BB + b) * UU + u];
        const float h2 = H[((size_t)i2 * BB + b) * UU + u];
        const float h3 = H[((size_t)i3 * BB + b) * UU + u];
        const float c0 = C[((size_t)i0 * BB + b) * UU + u];
        const float c1 = C[((size_t)i1 * BB + b) * UU + u];
        const float c2 = C[((size_t)i2 * BB + b) * UU + u];
        const float c3 = C[((size_t)i3 * BB + b) * UU + u];
        s_x[u]        = p.tree_e[((size_t)b * TT + i) * UU + u];   // f32 — no rounding seed
        s_hk[u]       = h0;
        s_hk[256 + u] = h1;
        s_hk[512 + u] = h2;
        s_hk[768 + u] = h3;
        s_hj[u]       = h0 + h1 + h2 + h3;
        __syncthreads();

        float zi = 0.f, zj = 0.f, zo = 0.f, fx = 0.f;
        float f0 = 0.f, f1 = 0.f, f2 = 0.f, f3 = 0.f;
        for (int r = 0; r < 256; ++r) {           // x rows [0,256)
            const float xv = s_x[r];
            const size_t ro = (size_t)r * 1024;
            zi = fmaf(xv, ld1<F32>(W, ro + u),       zi);
            zj = fmaf(xv, ld1<F32>(W, ro + 256 + u), zj);
            zo = fmaf(xv, ld1<F32>(W, ro + 512 + u), zo);
            fx = fmaf(xv, ld1<F32>(W, ro + 768 + u), fx);
        }
        for (int r = 0; r < 256; ++r) {           // h rows [256,512)
            const size_t ro = (size_t)(256 + r) * 1024;
            const float hjv = s_hj[r];
            zi = fmaf(hjv, ld1<F32>(W, ro + u),       zi);
            zj = fmaf(hjv, ld1<F32>(W, ro + 256 + u), zj);
            zo = fmaf(hjv, ld1<F32>(W, ro + 512 + u), zo);
            const float wf = ld1<F32>(W, ro + 768 + u);  // f col, shared by all children
            f0 = fmaf(s_hk[r],       wf, f0);
            f1 = fmaf(s_hk[256 + r], wf, f1);
            f2 = fmaf(s_hk[512 + r], wf, f2);
            f3 = fmaf(s_hk[768 + r], wf, f3);
        }
        zi += ld1<F32>(bias, u);
        zj += ld1<F32>(bias, 256 + u);
        zo += ld1<F32>(bias, 512 + u);
        fx += ld1<F32>(bias, 768 + u) + 1.0f;    // bias + FORGET_BIAS

        const float fsum = c0 * sigm(fx + f0) + c1 * sigm(fx + f1)
                         + c2 * sigm(fx + f2) + c3 * sigm(fx + f3);
        const float nc = fsum + sigm(zi) * tanhf(zj);
        const float nh = tanhf(nc) * sigm(zo);
        __syncthreads();                          // all threads done reading LDS
        H[((size_t)(i + 1) * BB + b) * UU + u] = nh;
        C[((size_t)(i + 1) * BB + b) * UU + u] = nc;
    }
}

template<bool F32>
__device__ void run_token_l0(int b, const P& p, float* smem, bool is_bw) {
    const int u = threadIdx.x;
    float* s_xh = smem;          // [0,256)=x, [256,512)=h
    const int len = p.token_length[b];
    const void* W0 = is_bw ? p.bw0_W : p.fw0_W;
    const void* b0 = is_bw ? p.bw0_b : p.fw0_b;

    float c0 = 0.f;
    s_xh[256 + u] = 0.f;
    for (int t = 0; t < len; ++t) {
        const int row = is_bw ? (len - 1 - t) : t;
        s_xh[u] = bf2f(p.token_e[((size_t)b * LL + row) * UU + u]);
        __syncthreads();
        const float nh = lstm_step<512, F32>(W0, b0, s_xh, c0);
        p.x1[((size_t)b * LL + row) * 512 + (is_bw ? 256 : 0) + u] = f2bf(nh);
        __syncthreads();
        s_xh[256 + u] = nh;
    }
}

template<bool F32>
__device__ void run_act_dq(int b, const P& p, float* smem) {
    const int u = threadIdx.x;
    float* s_xh0 = smem;         // [0,512)
    float* s_xh1 = smem + 512;   // [0,512)

    { // act: layout [0,64)=x, [64,320)=h
        const int len = p.history_action_length[b];
        float ca0 = 0.f, ca1 = 0.f, h1last = 0.f;
        s_xh0[ADIM + u] = 0.f;
        s_xh1[256 + u]  = 0.f;
        for (int t = 0; t < len; ++t) {
            const int aid = p.history_action_id[b * AA + t];
            if (u < ADIM) s_xh0[u] = ld1<F32>(p.act_emb, (size_t)aid * ADIM + u);
            __syncthreads();
            const float nh0 = lstm_step<320, F32>(p.act0_W, p.act0_b, s_xh0, ca0);
            __syncthreads();
            s_xh0[ADIM + u] = nh0;
            s_xh1[u]        = nh0;
            __syncthreads();
            const float nh1 = lstm_step<512, F32>(p.act1_W, p.act1_b, s_xh1, ca1);
            __syncthreads();
            s_xh1[256 + u] = nh1;
            h1last = nh1;
        }
        p.act_h[b * UU + u] = h1last;
    }
    __syncthreads();
    { // deque
        const int len = p.deque_length[b];
        float cd0 = 0.f, cd1 = 0.f, h1last = 0.f;
        s_xh0[256 + u] = 0.f;
        s_xh1[256 + u] = 0.f;
        for (int t = 0; t < len; ++t) {
            s_xh0[u] = bf2f(p.deque_e[((size_t)b * DQN + t) * UU + u]);
            __syncthreads();
            const float nh0 = lstm_step<512, F32>(p.dq0_W, p.dq0_b, s_xh0, cd0);
            __syncthreads();
            s_xh0[256 + u] = nh0;
            s_xh1[u]       = nh0;
            __syncthreads();
            const float nh1 = lstm_step<512, F32>(p.dq1_W, p.dq1_b, s_xh1, cd1);
            __syncthreads();
            s_xh1[256 + u] = nh1;
            h1last = nh1;
        }
        p.dq_h[b * UU + u] = h1last;
    }
}

__global__ __launch_bounds__(256) void phase1_kernel(P p) {
    __shared__ __align__(16) float smem[1536];
    const bool f32 = (p.flag[0] == 1);
    const int chain = blockIdx.x & 3;
    const int b     = blockIdx.x >> 2;
    if (f32) {
        if (chain == 0)      run_tree<true>(b, p, smem);
        else if (chain == 1) run_token_l0<true>(b, p, smem, false);
        else if (chain == 2) run_token_l0<true>(b, p, smem, true);
        else                 run_act_dq<true>(b, p, smem);
    } else {
        if (chain == 0)      run_tree<false>(b, p, smem);
        else if (chain == 1) run_token_l0<false>(b, p, smem, false);
        else if (chain == 2) run_token_l0<false>(b, p, smem, true);
        else                 run_act_dq<false>(b, p, smem);
    }
}

// ---------------------------------------------------------------------------
// Phase 2
// ---------------------------------------------------------------------------
template<bool F32>
__device__ void run_stack(int b, const P& p, float* smem) {
    const int u = threadIdx.x;
    float* s_xh0 = smem;         // [0,512)
    float* s_xh1 = smem + 512;   // [0,512)
    const int len = p.stack_length[b];
    float cs0 = 0.f, cs1 = 0.f, h1last = 0.f;
    s_xh0[256 + u] = 0.f;
    s_xh1[256 + u] = 0.f;
    for (int t = 0; t < len; ++t) {
        const int so = p.stack_order[b * SS + t];
        s_xh0[u] = p.H[((size_t)so * BB + b) * UU + u];
        __syncthreads();
        const float nh0 = lstm_step<512, F32>(p.stack0_W, p.stack0_b, s_xh0, cs0);
        __syncthreads();
        s_xh0[256 + u] = nh0;
        s_xh1[u]       = nh0;
        __syncthreads();
        const float nh1 = lstm_step<512, F32>(p.stack1_W, p.stack1_b, s_xh1, cs1);
        __syncthreads();
        s_xh1[256 + u] = nh1;
        h1last = nh1;
    }
    p.stack_h[b * UU + u] = h1last;
}

template<bool F32>
__device__ void run_token_l1(int b, const P& p, float* smem, bool is_bw) {
    const int u = threadIdx.x;
    float* s_xh = smem;          // [0,512)=x1 row, [512,768)=h
    const int len  = p.token_length[b];
    const int btop = p.buff_top_id[b];
    const void* W1 = is_bw ? p.bw1_W : p.fw1_W;
    const void* b1 = is_bw ? p.bw1_b : p.fw1_b;

    float c1 = 0.f, hlast = 0.f;
    s_xh[512 + u] = 0.f;
    for (int t = 0; t < len; ++t) {
        const int row = is_bw ? (len - 1 - t) : t;
        const ushort_t* xr = p.x1 + ((size_t)b * LL + row) * 512;
        s_xh[u]       = bf2f(xr[u]);
        s_xh[256 + u] = bf2f(xr[256 + u]);
        __syncthreads();
        const float nh = lstm_step<768, F32>(W1, b1, s_xh, c1);
        if (!is_bw) {
            if (t == btop) p.fw_top[b * UU + u] = nh;
        } else {
            if (t == 0)              p.bw_bottom[b * UU + u] = nh;
            if (t == len - 1 - btop) p.bw_top[b * UU + u]    = nh;
        }
        __syncthreads();
        s_xh[512 + u] = nh;
        hlast = nh;
    }
    if (!is_bw) p.fw1_h[b * UU + u] = hlast;
}

__global__ __launch_bounds__(256) void phase2_kernel(P p) {
    __shared__ __align__(16) float smem[1024];
    const bool f32 = (p.flag[0] == 1);
    const int chain = blockIdx.x % 3;
    const int b     = blockIdx.x / 3;
    if (f32) {
        if (chain == 0)      run_stack<true>(b, p, smem);
        else if (chain == 1) run_token_l1<true>(b, p, smem, false);
        else                 run_token_l1<true>(b, p, smem, true);
    } else {
        if (chain == 0)      run_stack<false>(b, p, smem);
        else if (chain == 1) run_token_l1<false>(b, p, smem, false);
        else                 run_token_l1<false>(b, p, smem, true);
    }
}

// ---------------------------------------------------------------------------
// Final + pipeline tracers
// ---------------------------------------------------------------------------
template<bool F32>
__device__ __forceinline__ void st_out(void* out, int i, float v) {
    if constexpr (F32) reinterpret_cast<float*>(out)[i] = v;
    else               reinterpret_cast<__hip_bfloat16*>(out)[i] = __float2bfloat16(v);
}

template<bool F32>
__device__ void final_impl(const P& p, void* out, float* s_f) {
    const int b = blockIdx.x;
    const int u = threadIdx.x;
    s_f[u]        = p.stack_h[b * UU + u];
    s_f[256 + u]  = p.fw1_h[b * UU + u] - p.fw_top[b * UU + u];
    s_f[512 + u]  = p.bw_top[b * UU + u] - p.bw_bottom[b * UU + u];
    s_f[768 + u]  = p.act_h[b * UU + u];
    s_f[1024 + u] = p.dq_h[b * UU + u];
    __syncthreads();
    if (u < NAOUT) {
        float acc = ld1<F32>(p.fin_b, u);
        for (int r = 0; r < 1280; ++r)
            acc = fmaf(s_f[r], ld1<F32>(p.fin_W, (size_t)r * NAOUT + u), acc);
        acc = fmaxf(acc, 0.f);
        st_out<F32>(out, b * NAOUT + u, acc);
    }
    if (b == 0 && u == 0) {
        const uint_t POIS = 0xAAAAAAAAu;
        const uint_t* te = reinterpret_cast<const uint_t*>(p.tree_e);
        const uint_t* x1 = reinterpret_cast<const uint_t*>(p.x1);
        const uint_t* sh = reinterpret_cast<const uint_t*>(p.stack_h);
        bool te_p = true, x1_p = true;
        for (int i = 0; i < 8; ++i) { te_p &= (te[i] == POIS); x1_p &= (x1[i] == POIS); }
        bool sh_p = (sh[0] == POIS) && (sh[1] == POIS);
        float sent = 0.f;
        if (te_p)      sent = 3000.f;
        else if (x1_p) sent = 4000.f;
        else if (sh_p) sent = 5000.f;
        else if (*reinterpret_cast<const uint_t*>(p.flag) == POIS) sent = 6000.f;
        if (sent > 0.f) st_out<F32>(out, 0, sent);
    }
}

__global__ __launch_bounds__(256) void final_kernel(P p, void* out) {
    __shared__ __align__(16) float s_f[1280];
    if (p.flag[0] == 1) final_impl<true>(p, out, s_f);
    else                final_impl<false>(p, out, s_f);
}

// ---------------------------------------------------------------------------
extern "C" void kernel_launch(void* const* d_in, const int* in_sizes, int n_in,
                              void* d_out, int out_size, void* d_ws, size_t ws_size,
                              hipStream_t stream) {
    if (n_in != 43) {
        sentinel_kernel<<<1, 64, 0, stream>>>(d_out, 9000.f + (float)n_in);
        return;
    }
    if (out_size != NAOUT * BB) {
        sentinel_kernel<<<1, 64, 0, stream>>>(d_out, 8000.f);
        return;
    }

    P p;
    p.tree_word_id          = (const int*)d_in[0];
    p.tree_pos_id           = (const int*)d_in[1];
    p.token_word_id         = (const int*)d_in[2];
    p.token_pos_id          = (const int*)d_in[3];
    p.history_action_id     = (const int*)d_in[4];
    p.buff_top_id           = (const int*)d_in[5];
    p.deque_word_id         = (const int*)d_in[6];
    p.deque_pos_id          = (const int*)d_in[7];
    p.deque_length          = (const int*)d_in[8];
    p.children_order        = (const int*)d_in[9];
    p.stack_order           = (const int*)d_in[10];
    p.stack_length          = (const int*)d_in[11];
    p.token_length          = (const int*)d_in[12];
    p.history_action_length = (const int*)d_in[13];
    p.word_emb = d_in[14];
    p.pos_emb  = d_in[15];
    p.act_emb  = d_in[16];
    p.wd_W     = d_in[17];
    p.wd_b     = d_in[18];
    p.tree_W   = d_in[19];
    p.tree_b   = d_in[20];
    p.stack0_W = d_in[21];
    p.stack0_b = d_in[22];
    p.stack1_W = d_in[23];
    p.stack1_b = d_in[24];
    p.fw0_W    = d_in[25];
    p.fw0_b    = d_in[26];
    p.bw0_W    = d_in[27];
    p.bw0_b    = d_in[28];
    p.fw1_W    = d_in[29];
    p.fw1_b    = d_in[30];
    p.bw1_W    = d_in[31];
    p.bw1_b    = d_in[32];
    p.act0_W   = d_in[33];
    p.act0_b   = d_in[34];
    p.act1_W   = d_in[35];
    p.act1_b   = d_in[36];
    p.dq0_W    = d_in[37];
    p.dq0_b    = d_in[38];
    p.dq1_W    = d_in[39];
    p.dq1_b    = d_in[40];
    p.fin_W    = d_in[41];
    p.fin_b    = d_in[42];

    char* base = (char*)d_ws;
    size_t off = 0;
    p.flag = (int*)(base + off);           off += 16;
    p.stack_h   = (float*)(base + off);    off += (size_t)BB * UU * 4;
    p.fw1_h     = (float*)(base + off);    off += (size_t)BB * UU * 4;
    p.fw_top    = (float*)(base + off);    off += (size_t)BB * UU * 4;
    p.bw_top    = (float*)(base + off);    off += (size_t)BB * UU * 4;
    p.bw_bottom = (float*)(base + off);    off += (size_t)BB * UU * 4;
    p.act_h     = (float*)(base + off);    off += (size_t)BB * UU * 4;
    p.dq_h      = (float*)(base + off);    off += (size_t)BB * UU * 4;
    p.tree_e  = (float*)(base + off);      off += (size_t)BB * TT * UU * 4;   // f32 now
    p.token_e = (ushort_t*)(base + off);   off += (size_t)BB * LL * UU * 2;
    p.deque_e = (ushort_t*)(base + off);   off += (size_t)BB * DQN * UU * 2;
    p.x1      = (ushort_t*)(base + off);   off += (size_t)BB * LL * 512 * 2;
    p.H       = (float*)(base + off);      off += (size_t)(TT + 1) * BB * UU * 4;
    p.C       = (float*)(base + off);      off += (size_t)(TT + 1) * BB * UU * 4;
    // ~37.6 MiB

    if (ws_size < off) {
        sentinel_kernel<<<1, 64, 0, stream>>>(d_out, 7000.f + (float)(ws_size >> 20));
        return;
    }

    detect_kernel<<<1, 64, 0, stream>>>((const uint_t*)d_in[14], p.flag);
    embed_kernel<<<dim3(BB * TT + BB * LL + BB * DQN), dim3(256), 0, stream>>>(p);
    phase1_kernel<<<dim3(4 * BB), dim3(256), 0, stream>>>(p);
    phase2_kernel<<<dim3(3 * BB), dim3(256), 0, stream>>>(p);
    final_kernel<<<dim3(BB), dim3(256), 0, stream>>>(p, d_out);
}